// Round 15
// baseline (191.774 us; speedup 1.0000x reference)
//
#include <hip/hip_runtime.h>
#include <hip/hip_bf16.h>
#include <math.h>

#define N_NODES 50000
#define N_EDGES 800000
#define IN_DIM  256
#define HID     64
#define H1      4
#define F1      256   // H1*HID
#define NC      64
#define CHUNK   128
#define NB_SCAN 49    // ceil(50000/1024)
#define GEMM1_BLOCKS 800
#define FILL4_BLOCKS ((N_EDGES/4+255)/256)
#define HIST4_BLOCKS ((N_EDGES/4+255)/256)
#define PREPW_BLOCKS ((256*256 + 128*256 + 255)/256)
#define CASTX_BLOCKS (N_NODES*IN_DIM/8/256)   // 6250

typedef __attribute__((ext_vector_type(8))) short short8v;
typedef __attribute__((ext_vector_type(4))) float float4v;
typedef __attribute__((ext_vector_type(2))) float float2v;

__device__ __forceinline__ float bf2f(unsigned short u){
  union { unsigned int i; float f; } c; c.i = ((unsigned int)u) << 16; return c.f;
}
__device__ __forceinline__ float asf(unsigned int u){
  union { unsigned int i; float f; } c; c.i = u; return c.f;
}
// two bf16 packed in u32 -> float2 {low, high}
__device__ __forceinline__ float2v bf2x2(unsigned int u){
  float2v r; r.x = asf(u << 16); r.y = asf(u & 0xffff0000u); return r;
}

// ------- hist (int4, records per-edge slot) + weight prep + x->bf16 cast, fused ----------

__global__ __launch_bounds__(256) void hist_prepw_kernel(
    const int* __restrict__ dst, int* __restrict__ counts, int* __restrict__ eslot,
    const float* __restrict__ W1, const float* __restrict__ W2,
    const float* __restrict__ resW2,
    __hip_bfloat16* __restrict__ W1T, __hip_bfloat16* __restrict__ B2T,
    const float* __restrict__ x, __hip_bfloat16* __restrict__ xb){
  int b = blockIdx.x;
  if (b < HIST4_BLOCKS){
    int e4 = b*256 + threadIdx.x;
    if (e4 < N_EDGES/4){
      int4 d = ((const int4*)dst)[e4];
      int4 s;
      s.x = atomicAdd(&counts[d.x], 1);
      s.y = atomicAdd(&counts[d.y], 1);
      s.z = atomicAdd(&counts[d.z], 1);
      s.w = atomicAdd(&counts[d.w], 1);
      ((int4*)eslot)[e4] = s;              // slot of edge within its dst bucket
    }
  } else if (b < HIST4_BLOCKS + PREPW_BLOCKS){
    int i = (b - HIST4_BLOCKS)*256 + threadIdx.x;
    if (i < 256*256){
      int n = i >> 8, k = i & 255;
      W1T[n*256 + k] = __float2bfloat16(W1[k*256 + n]);
    } else if (i < 256*256 + 128*256){
      int j = i - 256*256;
      int n = j >> 8, k = j & 255;
      float v = (n < 64) ? W2[k*64 + n] : resW2[k*64 + (n - 64)];
      B2T[n*256 + k] = __float2bfloat16(v);
    }
  } else {
    int t = (b - HIST4_BLOCKS - PREPW_BLOCKS)*256 + threadIdx.x;  // 0..1.6M-1
    if (t < N_NODES*IN_DIM/8){
      const float4* xf = (const float4*)x;
      float4 v0 = xf[(size_t)t*2], v1 = xf[(size_t)t*2+1];
      __hip_bfloat16 o[8] = {__float2bfloat16(v0.x),__float2bfloat16(v0.y),
                             __float2bfloat16(v0.z),__float2bfloat16(v0.w),
                             __float2bfloat16(v1.x),__float2bfloat16(v1.y),
                             __float2bfloat16(v1.z),__float2bfloat16(v1.w)};
      *(int4*)&xb[(size_t)t*8] = *(int4*)o;
    }
  }
}

// ---------------- scans ----------------

__global__ __launch_bounds__(1024) void scan1_kernel(const int* __restrict__ counts,
                                                     int* __restrict__ part,
                                                     int* __restrict__ bsum, int n){
  __shared__ int wsum[16];
  int b = blockIdx.x, tid = threadIdx.x;
  int i = b*1024 + tid;
  int lane = tid & 63, wid = tid >> 6;
  int x = (i < n) ? counts[i] : 0;
  #pragma unroll
  for (int off = 1; off < 64; off <<= 1){ int t = __shfl_up(x, off); if (lane >= off) x += t; }
  if (lane == 63) wsum[wid] = x;
  __syncthreads();
  if (wid == 0 && lane < 16){
    int w = wsum[lane];
    #pragma unroll
    for (int off = 1; off < 16; off <<= 1){ int t = __shfl_up(w, off); if (lane >= off) w += t; }
    wsum[lane] = w;
  }
  __syncthreads();
  int incl = x + (wid ? wsum[wid-1] : 0);
  if (i < n) part[i] = incl;
  if (tid == 1023) bsum[b] = incl;
}

// scan3: exclusive row_ptr; block-sum scan redundantly in-block (no scan2, no cursor)
__global__ __launch_bounds__(1024) void scan3_kernel(const int* __restrict__ part,
                                                     const int* __restrict__ bsum,
                                                     int* __restrict__ row_ptr, int n){
  __shared__ int off_s;
  int b = blockIdx.x, tid = threadIdx.x;
  if (tid < 64){
    int orig = (tid < NB_SCAN) ? bsum[tid] : 0;
    int x = orig;
    #pragma unroll
    for (int o = 1; o < 64; o <<= 1){ int t = __shfl_up(x, o); if (tid >= o) x += t; }
    if (tid == b) off_s = x - orig;        // exclusive prefix of this block
  }
  __syncthreads();
  int i = b*1024 + tid;
  if (i < n) row_ptr[i+1] = part[i] + off_s;
  if (i == 0) row_ptr[0] = 0;
}

// ---------------- bf16 MFMA GEMM, BK=64, OPERAND-SWAPPED (C^T fragment layout) ----------

template<int LAYER>
__device__ __forceinline__ void gemm_body(
    const __hip_bfloat16* __restrict__ A,
    const __hip_bfloat16* __restrict__ BT,
    __hip_bfloat16* __restrict__ Fb,
    float* __restrict__ Res,
    float* __restrict__ el, float* __restrict__ er,
    const float* __restrict__ aL, const float* __restrict__ aR,
    int M, int bm, int bn)
{
  constexpr int K = 256;
  __shared__ __hip_bfloat16 As[128*72];
  __shared__ __hip_bfloat16 Bs[128*72];
  int tid = threadIdx.x;
  int lane = tid & 63, w = tid >> 6;
  int wr = w >> 1, wc = w & 1;
  int l15 = lane & 15, l4 = lane >> 4;

  float4v acc[4][4];
  #pragma unroll
  for (int i=0;i<4;i++)
    #pragma unroll
    for (int j=0;j<4;j++) acc[i][j] = (float4v){0.f,0.f,0.f,0.f};

  for (int kt = 0; kt < K; kt += 64){
    #pragma unroll
    for (int it = 0; it < 4; it++){
      int chunk = tid + it*256;          // 0..1023
      int r = chunk >> 3, kc = (chunk & 7)*8;
      int arow = bm*128 + r;
      int4 va = make_int4(0,0,0,0);
      if (arow < M) va = *(const int4*)&A[(size_t)arow*K + kt + kc];
      *(int4*)&As[r*72 + kc] = va;
      int brow = bn*128 + r;
      int4 vb = *(const int4*)&BT[(size_t)brow*K + kt + kc];
      *(int4*)&Bs[r*72 + kc] = vb;
    }
    __syncthreads();
    short8v af[4][2], bfr[4][2];
    #pragma unroll
    for (int mi=0;mi<4;mi++)
      #pragma unroll
      for (int kf=0;kf<2;kf++)
        af[mi][kf] = *(const short8v*)&As[(wr*64 + mi*16 + l15)*72 + kf*32 + l4*8];
    #pragma unroll
    for (int ni=0;ni<4;ni++)
      #pragma unroll
      for (int kf=0;kf<2;kf++)
        bfr[ni][kf] = *(const short8v*)&Bs[(wc*64 + ni*16 + l15)*72 + kf*32 + l4*8];
    // swapped operands: D = B^T * A^T = C^T
    #pragma unroll
    for (int mi=0;mi<4;mi++)
      #pragma unroll
      for (int ni=0;ni<4;ni++){
        acc[mi][ni] = __builtin_amdgcn_mfma_f32_16x16x32_bf16(bfr[ni][0], af[mi][0], acc[mi][ni], 0,0,0);
        acc[mi][ni] = __builtin_amdgcn_mfma_f32_16x16x32_bf16(bfr[ni][1], af[mi][1], acc[mi][ni], 0,0,0);
      }
    __syncthreads();
  }

  // epilogue: lane holds C[row = bm*128 + wr*64 + mi*16 + l15][col-frag ni*16 + l4*4 + r]
  if (LAYER == 1){
    int h = bn*2 + wc;
    float aLv[4][4], aRv[4][4];
    #pragma unroll
    for (int ni=0;ni<4;ni++){
      float4 a = *(const float4*)&aL[h*64 + ni*16 + l4*4];
      float4 bvv = *(const float4*)&aR[h*64 + ni*16 + l4*4];
      aLv[ni][0]=a.x; aLv[ni][1]=a.y; aLv[ni][2]=a.z; aLv[ni][3]=a.w;
      aRv[ni][0]=bvv.x; aRv[ni][1]=bvv.y; aRv[ni][2]=bvv.z; aRv[ni][3]=bvv.w;
    }
    #pragma unroll
    for (int mi=0;mi<4;mi++){
      int row = bm*128 + wr*64 + mi*16 + l15;
      float sl = 0.f, sr = 0.f;
      ushort4 packs[4];
      #pragma unroll
      for (int ni=0;ni<4;ni++){
        __hip_bfloat16 o[4];
        #pragma unroll
        for (int r=0;r<4;r++){
          float v = acc[mi][ni][r];
          sl += v*aLv[ni][r]; sr += v*aRv[ni][r];
          o[r] = __float2bfloat16(v);
        }
        packs[ni] = *(ushort4*)o;
      }
      if (row < M){
        #pragma unroll
        for (int ni=0;ni<4;ni++)
          *(ushort4*)&Fb[(size_t)row*256 + h*64 + ni*16 + l4*4] = packs[ni];
      }
      sl += __shfl_xor(sl, 16); sl += __shfl_xor(sl, 32);
      sr += __shfl_xor(sr, 16); sr += __shfl_xor(sr, 32);
      if (l4 == 0 && row < M){ el[row*4 + h] = sl; er[row*4 + h] = sr; }
    }
  } else {
    if (wc == 0){
      float aLv[4][4], aRv[4][4];
      #pragma unroll
      for (int ni=0;ni<4;ni++){
        float4 a = *(const float4*)&aL[ni*16 + l4*4];
        float4 bvv = *(const float4*)&aR[ni*16 + l4*4];
        aLv[ni][0]=a.x; aLv[ni][1]=a.y; aLv[ni][2]=a.z; aLv[ni][3]=a.w;
        aRv[ni][0]=bvv.x; aRv[ni][1]=bvv.y; aRv[ni][2]=bvv.z; aRv[ni][3]=bvv.w;
      }
      #pragma unroll
      for (int mi=0;mi<4;mi++){
        int row = bm*128 + wr*64 + mi*16 + l15;
        float sl = 0.f, sr = 0.f;
        ushort4 packs[4];
        #pragma unroll
        for (int ni=0;ni<4;ni++){
          __hip_bfloat16 o[4];
          #pragma unroll
          for (int r=0;r<4;r++){
            float v = acc[mi][ni][r];
            sl += v*aLv[ni][r]; sr += v*aRv[ni][r];
            o[r] = __float2bfloat16(v);
          }
          packs[ni] = *(ushort4*)o;
        }
        if (row < M){
          #pragma unroll
          for (int ni=0;ni<4;ni++)
            *(ushort4*)&Fb[(size_t)row*64 + ni*16 + l4*4] = packs[ni];
        }
        sl += __shfl_xor(sl, 16); sl += __shfl_xor(sl, 32);
        sr += __shfl_xor(sr, 16); sr += __shfl_xor(sr, 32);
        if (l4 == 0 && row < M){ el[row] = sl; er[row] = sr; }
      }
    } else {
      #pragma unroll
      for (int mi=0;mi<4;mi++){
        int row = bm*128 + wr*64 + mi*16 + l15;
        if (row < M){
          #pragma unroll
          for (int ni=0;ni<4;ni++){
            float4 o = make_float4(acc[mi][ni][0], acc[mi][ni][1], acc[mi][ni][2], acc[mi][ni][3]);
            *(float4*)&Res[(size_t)row*64 + ni*16 + l4*4] = o;
          }
        }
      }
    }
  }
}

// fused dispatch: blocks [0,800) = layer-1 GEMM (XCD-paired swizzle);
// rest = atomic-free CSR fill, 4 edges/thread (int4 loads, 4 independent scatters).
__global__ __launch_bounds__(256) void gemm1_fill_kernel(
    const __hip_bfloat16* __restrict__ xb, const __hip_bfloat16* __restrict__ W1T,
    __hip_bfloat16* __restrict__ featb,
    float* __restrict__ el, float* __restrict__ er,
    const float* __restrict__ aL, const float* __restrict__ aR,
    const int* __restrict__ src, const int* __restrict__ dst,
    const int* __restrict__ row_ptr, const int* __restrict__ eslot,
    int* __restrict__ csr_src)
{
  int id = blockIdx.x;
  if (id < GEMM1_BLOCKS){
    int bn = (id >> 3) & 1;
    int bm = (id & 7) | ((id >> 4) << 3);
    if (bm*128 >= N_NODES) return;
    gemm_body<1>(xb, W1T, featb, nullptr, el, er, aL, aR, N_NODES, bm, bn);
  } else {
    int e4 = (id - GEMM1_BLOCKS)*256 + threadIdx.x;
    if (e4 < N_EDGES/4){
      int4 d  = ((const int4*)dst)[e4];
      int4 s  = ((const int4*)src)[e4];
      int4 sl = ((const int4*)eslot)[e4];
      csr_src[row_ptr[d.x] + sl.x] = s.x;
      csr_src[row_ptr[d.y] + sl.y] = s.y;
      csr_src[row_ptr[d.z] + sl.z] = s.z;
      csr_src[row_ptr[d.w] + sl.w] = s.w;
    }
  }
}

__global__ __launch_bounds__(256) void gemm2_kernel(
    const __hip_bfloat16* __restrict__ A, const __hip_bfloat16* __restrict__ BT,
    __hip_bfloat16* __restrict__ Fb, float* __restrict__ Res,
    float* __restrict__ el, float* __restrict__ er,
    const float* __restrict__ aL, const float* __restrict__ aR, int M)
{
  gemm_body<2>(A, BT, Fb, Res, el, er, aL, aR, M, blockIdx.x, 0);
}

// ---------------- fused softmax + aggregation, packed-f32 inner loop ----------------

__global__ __launch_bounds__(256) void agg1_kernel(const int* __restrict__ row_ptr,
                                                   const int* __restrict__ csr_src,
                                                   const float* __restrict__ el,
                                                   const float* __restrict__ er,
                                                   const __hip_bfloat16* __restrict__ featb,
                                                   const float* __restrict__ bias,
                                                   __hip_bfloat16* __restrict__ h1b, int N){
  __shared__ int   ssh[4][CHUNK];
  __shared__ float wsh[4][CHUNK][4];
  int lane = threadIdx.x & 63, wv = threadIdx.x >> 6;
  int n = blockIdx.x*4 + wv;
  if (n >= N) return;
  int rs = row_ptr[n], re = row_ptr[n+1];
  int half = lane >> 5;
  int l31 = lane & 31;
  int hl = l31 >> 3;                       // head of cols [l31*8, l31*8+8)
  float4 ern4 = *(const float4*)&er[(size_t)n*4];
  float ernv[4] = {ern4.x, ern4.y, ern4.z, ern4.w};
  float2v acc2[4];                         // 8 columns as 4 packed pairs
  #pragma unroll
  for (int j = 0; j < 4; j++) acc2[j] = (float2v){0.f, 0.f};
  float ssum4[4] = {0.f,0.f,0.f,0.f};

  for (int base = rs; base < re; base += CHUNK){
    int cnt = min(CHUNK, re - base);
    int padded = (cnt + 7) & ~7;
    // phase A: one lane per edge, exp computed once
    for (int t = lane; t < padded; t += 64){
      float w4[4] = {0.f,0.f,0.f,0.f};
      int s = 0;
      if (t < cnt){
        s = csr_src[base + t];
        float4 e4 = *(const float4*)&el[(size_t)s*4];
        float ev[4] = {e4.x, e4.y, e4.z, e4.w};
        #pragma unroll
        for (int h = 0; h < 4; h++){
          float e = ev[h] + ernv[h];
          e = e > 0.f ? e : 0.2f*e;
          float ex = __expf(e);
          w4[h] = ex;
          ssum4[h] += ex;
        }
      }
      ssh[wv][t] = s;
      *(float4*)&wsh[wv][t][0] = make_float4(w4[0], w4[1], w4[2], w4[3]);
    }
    // phase B: 8 edges per iteration, 4 independent 512B row loads per half-wave,
    // packed f32 FMA (v_pk_fma_f32) on bf16 pairs.
    for (int jb = 0; jb < padded; jb += 8){
      int t0 = jb + half, t1 = jb + 2 + half, t2 = jb + 4 + half, t3 = jb + 6 + half;
      int s0 = ssh[wv][t0], s1 = ssh[wv][t1], s2 = ssh[wv][t2], s3 = ssh[wv][t3];
      float w0 = wsh[wv][t0][hl], w1 = wsh[wv][t1][hl];
      float w2 = wsh[wv][t2][hl], w3 = wsh[wv][t3][hl];
      uint4 f0 = *(const uint4*)&featb[(size_t)s0*256 + l31*8];
      uint4 f1 = *(const uint4*)&featb[(size_t)s1*256 + l31*8];
      uint4 f2 = *(const uint4*)&featb[(size_t)s2*256 + l31*8];
      uint4 f3 = *(const uint4*)&featb[(size_t)s3*256 + l31*8];
      float2v W0 = (float2v){w0,w0}, W1 = (float2v){w1,w1};
      float2v W2 = (float2v){w2,w2}, W3 = (float2v){w3,w3};
      unsigned int u0[4] = {f0.x,f0.y,f0.z,f0.w};
      unsigned int u1[4] = {f1.x,f1.y,f1.z,f1.w};
      unsigned int u2[4] = {f2.x,f2.y,f2.z,f2.w};
      unsigned int u3[4] = {f3.x,f3.y,f3.z,f3.w};
      #pragma unroll
      for (int j = 0; j < 4; j++){
        acc2[j] += bf2x2(u0[j]) * W0;
        acc2[j] += bf2x2(u1[j]) * W1;
        acc2[j] += bf2x2(u2[j]) * W2;
        acc2[j] += bf2x2(u3[j]) * W3;
      }
    }
  }
  #pragma unroll
  for (int off = 32; off; off >>= 1)
    #pragma unroll
    for (int h = 0; h < 4; h++) ssum4[h] += __shfl_xor(ssum4[h], off);
  float acc[8];
  #pragma unroll
  for (int j = 0; j < 4; j++){ acc[2*j] = acc2[j].x; acc[2*j+1] = acc2[j].y; }
  #pragma unroll
  for (int q = 0; q < 8; q++) acc[q] += __shfl_xor(acc[q], 32);
  float inv = ssum4[hl] > 0.f ? 1.f/ssum4[hl] : 0.f;
  if (lane < 32){
    float4 b0 = *(const float4*)&bias[l31*8];
    float4 b1v = *(const float4*)&bias[l31*8 + 4];
    float bb[8] = {b0.x,b0.y,b0.z,b0.w,b1v.x,b1v.y,b1v.z,b1v.w};
    __hip_bfloat16 o[8];
    #pragma unroll
    for (int q = 0; q < 8; q++){
      float v = acc[q]*inv + bb[q];
      v = v > 0.f ? v : __expf(v) - 1.f;   // ELU
      o[q] = __float2bfloat16(v);
    }
    *(short8v*)&h1b[(size_t)n*256 + l31*8] = *(short8v*)o;
  }
}

__global__ __launch_bounds__(256) void agg2_kernel(const int* __restrict__ row_ptr,
                                                   const int* __restrict__ csr_src,
                                                   const float* __restrict__ el,
                                                   const float* __restrict__ er,
                                                   const __hip_bfloat16* __restrict__ f2b,
                                                   const float* __restrict__ res,
                                                   const float* __restrict__ bias,
                                                   float* __restrict__ out, int N){
  __shared__ int   ssh[4][CHUNK];
  __shared__ float wsh[4][CHUNK];
  int lane = threadIdx.x & 63, wv = threadIdx.x >> 6;
  int n = blockIdx.x*4 + wv;
  if (n >= N) return;
  int rs = row_ptr[n], re = row_ptr[n+1];
  int q4 = lane >> 4;                      // edge slot 0..3
  int l15 = lane & 15;
  float ern = er[n];
  float2v acc2[2] = {(float2v){0.f,0.f}, (float2v){0.f,0.f}};
  float ssum = 0.f;

  for (int base = rs; base < re; base += CHUNK){
    int cnt = min(CHUNK, re - base);
    int padded = (cnt + 15) & ~15;
    for (int t = lane; t < padded; t += 64){
      float w = 0.f; int s = 0;
      if (t < cnt){
        s = csr_src[base + t];
        float e = el[s] + ern;
        e = e > 0.f ? e : 0.2f*e;
        w = __expf(e);
        ssum += w;
      }
      ssh[wv][t] = s;
      wsh[wv][t] = w;
    }
    for (int jb = 0; jb < padded; jb += 16){
      int t0 = jb + q4, t1 = jb + 4 + q4, t2 = jb + 8 + q4, t3 = jb + 12 + q4;
      int s0 = ssh[wv][t0], s1 = ssh[wv][t1], s2 = ssh[wv][t2], s3 = ssh[wv][t3];
      float w0 = wsh[wv][t0], w1 = wsh[wv][t1], w2 = wsh[wv][t2], w3 = wsh[wv][t3];
      uint2 f0 = *(const uint2*)&f2b[(size_t)s0*NC + l15*4];
      uint2 f1 = *(const uint2*)&f2b[(size_t)s1*NC + l15*4];
      uint2 f2 = *(const uint2*)&f2b[(size_t)s2*NC + l15*4];
      uint2 f3 = *(const uint2*)&f2b[(size_t)s3*NC + l15*4];
      float2v W0 = (float2v){w0,w0}, W1 = (float2v){w1,w1};
      float2v W2 = (float2v){w2,w2}, W3 = (float2v){w3,w3};
      acc2[0] += bf2x2(f0.x) * W0; acc2[1] += bf2x2(f0.y) * W0;
      acc2[0] += bf2x2(f1.x) * W1; acc2[1] += bf2x2(f1.y) * W1;
      acc2[0] += bf2x2(f2.x) * W2; acc2[1] += bf2x2(f2.y) * W2;
      acc2[0] += bf2x2(f3.x) * W3; acc2[1] += bf2x2(f3.y) * W3;
    }
  }
  #pragma unroll
  for (int off = 32; off; off >>= 1) ssum += __shfl_xor(ssum, off);
  float acc[4] = {acc2[0].x, acc2[0].y, acc2[1].x, acc2[1].y};
  #pragma unroll
  for (int q = 0; q < 4; q++){
    acc[q] += __shfl_xor(acc[q], 16);
    acc[q] += __shfl_xor(acc[q], 32);
  }
  float inv = ssum > 0.f ? 1.f/ssum : 0.f;
  if (lane < 16){
    float4 r4 = *(const float4*)&res[(size_t)n*NC + l15*4];
    float4 b4 = *(const float4*)&bias[l15*4];
    float4 o;
    o.x = acc[0]*inv + r4.x + b4.x;
    o.y = acc[1]*inv + r4.y + b4.y;
    o.z = acc[2]*inv + r4.z + b4.z;
    o.w = acc[3]*inv + r4.w + b4.w;
    *(float4*)&out[(size_t)n*NC + l15*4] = o;
  }
}

// ---------------- launch ----------------

extern "C" void kernel_launch(void* const* d_in, const int* in_sizes, int n_in,
                              void* d_out, int out_size, void* d_ws, size_t ws_size,
                              hipStream_t stream){
  const float* x     = (const float*)d_in[0];
  const float* W1    = (const float*)d_in[1];
  const float* aL1   = (const float*)d_in[2];
  const float* aR1   = (const float*)d_in[3];
  const float* b1    = (const float*)d_in[4];
  const float* W2    = (const float*)d_in[5];
  const float* aL2   = (const float*)d_in[6];
  const float* aR2   = (const float*)d_in[7];
  const float* b2    = (const float*)d_in[8];
  const float* resW2 = (const float*)d_in[9];
  const int*   src   = (const int*)d_in[10];
  const int*   dst   = (const int*)d_in[11];
  float* out = (float*)d_out;

  char* p = (char*)d_ws;
  auto alloc = [&](size_t bytes)->void*{
    void* r = (void*)p; p += (bytes + 255) & ~(size_t)255; return r;
  };
  __hip_bfloat16* xb    = (__hip_bfloat16*)alloc((size_t)N_NODES*IN_DIM*2);
  __hip_bfloat16* featb = (__hip_bfloat16*)alloc((size_t)N_NODES*F1*2);
  __hip_bfloat16* h1b   = (__hip_bfloat16*)alloc((size_t)N_NODES*F1*2);
  __hip_bfloat16* f2b   = (__hip_bfloat16*)alloc((size_t)N_NODES*NC*2);
  float* res   = (float*)alloc((size_t)N_NODES*NC*4);
  float* el1   = (float*)alloc((size_t)N_NODES*H1*4);
  float* er1   = (float*)alloc((size_t)N_NODES*H1*4);
  float* el2   = (float*)alloc((size_t)N_NODES*4);
  float* er2   = (float*)alloc((size_t)N_NODES*4);
  int* counts  = (int*)alloc((size_t)N_NODES*4);
  int* part    = (int*)alloc((size_t)N_NODES*4);
  int* bsum    = (int*)alloc((size_t)64*4);
  int* row_ptr = (int*)alloc((size_t)(N_NODES+1)*4);
  int* eslot   = (int*)alloc((size_t)N_EDGES*4);
  int* csr_src = (int*)alloc((size_t)N_EDGES*4);
  __hip_bfloat16* W1T = (__hip_bfloat16*)alloc((size_t)256*256*2);
  __hip_bfloat16* B2T = (__hip_bfloat16*)alloc((size_t)128*256*2);

  int nb = (N_NODES + 1023)/1024;
  hipMemsetAsync(counts, 0, (size_t)N_NODES*4, stream);
  hist_prepw_kernel<<<HIST4_BLOCKS + PREPW_BLOCKS + CASTX_BLOCKS, 256, 0, stream>>>(
      dst, counts, eslot, W1, W2, resW2, W1T, B2T, x, xb);
  scan1_kernel<<<nb, 1024, 0, stream>>>(counts, part, bsum, N_NODES);
  scan3_kernel<<<nb, 1024, 0, stream>>>(part, bsum, row_ptr, N_NODES);

  // fused: layer-1 GEMM (blocks 0..799, XCD-paired) + atomic-free 4-wide CSR fill
  gemm1_fill_kernel<<<GEMM1_BLOCKS + FILL4_BLOCKS, 256, 0, stream>>>(
      xb, W1T, featb, el1, er1, aL1, aR1, src, dst, row_ptr, eslot, csr_src);

  agg1_kernel<<<(N_NODES+3)/4, 256, 0, stream>>>(row_ptr, csr_src, el1, er1, featb, b1, h1b, N_NODES);

  gemm2_kernel<<<(N_NODES+127)/128, 256, 0, stream>>>(h1b, B2T, f2b, res,
                                                      el2, er2, aL2, aR2, N_NODES);
  agg2_kernel<<<(N_NODES+3)/4, 256, 0, stream>>>(row_ptr, csr_src, el2, er2, f2b, res, b2, out, N_NODES);
}

// Round 16
// 187.354 us; speedup vs baseline: 1.0236x; 1.0236x over previous
//
#include <hip/hip_runtime.h>
#include <hip/hip_bf16.h>
#include <math.h>

#define N_NODES 50000
#define N_EDGES 800000
#define IN_DIM  256
#define HID     64
#define H1      4
#define F1      256   // H1*HID
#define NC      64
#define CHUNK   128
#define NB_SCAN 49    // ceil(50000/1024)
#define GEMM1_BLOCKS 800
#define FILL_BLOCKS  ((N_EDGES+255)/256)
#define HIST4_BLOCKS ((N_EDGES/4+255)/256)

typedef __attribute__((ext_vector_type(8))) short short8v;
typedef __attribute__((ext_vector_type(4))) float float4v;

__device__ __forceinline__ float bf2f(unsigned short u){
  union { unsigned int i; float f; } c; c.i = ((unsigned int)u) << 16; return c.f;
}

// ---------------- hist (int4, records per-edge slot) + weight prep, fused ----------------

__global__ __launch_bounds__(256) void hist_prepw_kernel(
    const int* __restrict__ dst, int* __restrict__ counts, int* __restrict__ eslot,
    const float* __restrict__ W1, const float* __restrict__ W2,
    const float* __restrict__ resW2,
    __hip_bfloat16* __restrict__ W1T, __hip_bfloat16* __restrict__ B2T){
  int b = blockIdx.x;
  if (b < HIST4_BLOCKS){
    int e4 = b*256 + threadIdx.x;
    if (e4 < N_EDGES/4){
      int4 d = ((const int4*)dst)[e4];
      int4 s;
      s.x = atomicAdd(&counts[d.x], 1);
      s.y = atomicAdd(&counts[d.y], 1);
      s.z = atomicAdd(&counts[d.z], 1);
      s.w = atomicAdd(&counts[d.w], 1);
      ((int4*)eslot)[e4] = s;              // slot of edge within its dst bucket
    }
  } else {
    int i = (b - HIST4_BLOCKS)*256 + threadIdx.x;
    if (i < 256*256){
      int n = i >> 8, k = i & 255;
      W1T[n*256 + k] = __float2bfloat16(W1[k*256 + n]);
    } else if (i < 256*256 + 128*256){
      int j = i - 256*256;
      int n = j >> 8, k = j & 255;
      float v = (n < 64) ? W2[k*64 + n] : resW2[k*64 + (n - 64)];
      B2T[n*256 + k] = __float2bfloat16(v);
    }
  }
}

// ---------------- scans ----------------

__global__ __launch_bounds__(1024) void scan1_kernel(const int* __restrict__ counts,
                                                     int* __restrict__ part,
                                                     int* __restrict__ bsum, int n){
  __shared__ int wsum[16];
  int b = blockIdx.x, tid = threadIdx.x;
  int i = b*1024 + tid;
  int lane = tid & 63, wid = tid >> 6;
  int x = (i < n) ? counts[i] : 0;
  #pragma unroll
  for (int off = 1; off < 64; off <<= 1){ int t = __shfl_up(x, off); if (lane >= off) x += t; }
  if (lane == 63) wsum[wid] = x;
  __syncthreads();
  if (wid == 0 && lane < 16){
    int w = wsum[lane];
    #pragma unroll
    for (int off = 1; off < 16; off <<= 1){ int t = __shfl_up(w, off); if (lane >= off) w += t; }
    wsum[lane] = w;
  }
  __syncthreads();
  int incl = x + (wid ? wsum[wid-1] : 0);
  if (i < n) part[i] = incl;
  if (tid == 1023) bsum[b] = incl;
}

// scan3: exclusive row_ptr; block-sum scan redundantly in-block (no scan2, no cursor)
__global__ __launch_bounds__(1024) void scan3_kernel(const int* __restrict__ part,
                                                     const int* __restrict__ bsum,
                                                     int* __restrict__ row_ptr, int n){
  __shared__ int off_s;
  int b = blockIdx.x, tid = threadIdx.x;
  if (tid < 64){
    int orig = (tid < NB_SCAN) ? bsum[tid] : 0;
    int x = orig;
    #pragma unroll
    for (int o = 1; o < 64; o <<= 1){ int t = __shfl_up(x, o); if (tid >= o) x += t; }
    if (tid == b) off_s = x - orig;        // exclusive prefix of this block
  }
  __syncthreads();
  int i = b*1024 + tid;
  if (i < n) row_ptr[i+1] = part[i] + off_s;
  if (i == 0) row_ptr[0] = 0;
}

// ---------------- bf16 MFMA GEMM, BK=64, OPERAND-SWAPPED (C^T fragment layout) ----------

template<int LAYER, bool AFP32>
__device__ __forceinline__ void gemm_body(
    const void* __restrict__ Araw,
    const __hip_bfloat16* __restrict__ BT,
    __hip_bfloat16* __restrict__ Fb,
    float* __restrict__ Res,
    float* __restrict__ el, float* __restrict__ er,
    const float* __restrict__ aL, const float* __restrict__ aR,
    int M, int bm, int bn)
{
  constexpr int K = 256;
  __shared__ __hip_bfloat16 As[128*72];
  __shared__ __hip_bfloat16 Bs[128*72];
  int tid = threadIdx.x;
  int lane = tid & 63, w = tid >> 6;
  int wr = w >> 1, wc = w & 1;
  int l15 = lane & 15, l4 = lane >> 4;

  float4v acc[4][4];
  #pragma unroll
  for (int i=0;i<4;i++)
    #pragma unroll
    for (int j=0;j<4;j++) acc[i][j] = (float4v){0.f,0.f,0.f,0.f};

  for (int kt = 0; kt < K; kt += 64){
    #pragma unroll
    for (int it = 0; it < 4; it++){
      int chunk = tid + it*256;          // 0..1023
      int r = chunk >> 3, kc = (chunk & 7)*8;
      int arow = bm*128 + r;
      if (AFP32){
        const float* Af = (const float*)Araw;
        float4 v0 = make_float4(0,0,0,0), v1 = make_float4(0,0,0,0);
        if (arow < M){
          v0 = *(const float4*)&Af[(size_t)arow*K + kt + kc];
          v1 = *(const float4*)&Af[(size_t)arow*K + kt + kc + 4];
        }
        __hip_bfloat16 t[8] = {__float2bfloat16(v0.x),__float2bfloat16(v0.y),
                               __float2bfloat16(v0.z),__float2bfloat16(v0.w),
                               __float2bfloat16(v1.x),__float2bfloat16(v1.y),
                               __float2bfloat16(v1.z),__float2bfloat16(v1.w)};
        *(int4*)&As[r*72 + kc] = *(int4*)t;
      } else {
        const __hip_bfloat16* Ab = (const __hip_bfloat16*)Araw;
        int4 va = make_int4(0,0,0,0);
        if (arow < M) va = *(const int4*)&Ab[(size_t)arow*K + kt + kc];
        *(int4*)&As[r*72 + kc] = va;
      }
      int brow = bn*128 + r;
      int4 vb = *(const int4*)&BT[(size_t)brow*K + kt + kc];
      *(int4*)&Bs[r*72 + kc] = vb;
    }
    __syncthreads();
    short8v af[4][2], bfr[4][2];
    #pragma unroll
    for (int mi=0;mi<4;mi++)
      #pragma unroll
      for (int kf=0;kf<2;kf++)
        af[mi][kf] = *(const short8v*)&As[(wr*64 + mi*16 + l15)*72 + kf*32 + l4*8];
    #pragma unroll
    for (int ni=0;ni<4;ni++)
      #pragma unroll
      for (int kf=0;kf<2;kf++)
        bfr[ni][kf] = *(const short8v*)&Bs[(wc*64 + ni*16 + l15)*72 + kf*32 + l4*8];
    // swapped operands: D = B^T * A^T = C^T
    #pragma unroll
    for (int mi=0;mi<4;mi++)
      #pragma unroll
      for (int ni=0;ni<4;ni++){
        acc[mi][ni] = __builtin_amdgcn_mfma_f32_16x16x32_bf16(bfr[ni][0], af[mi][0], acc[mi][ni], 0,0,0);
        acc[mi][ni] = __builtin_amdgcn_mfma_f32_16x16x32_bf16(bfr[ni][1], af[mi][1], acc[mi][ni], 0,0,0);
      }
    __syncthreads();
  }

  // epilogue: lane holds C[row = bm*128 + wr*64 + mi*16 + l15][col-frag ni*16 + l4*4 + r]
  if (LAYER == 1){
    int h = bn*2 + wc;
    float aLv[4][4], aRv[4][4];
    #pragma unroll
    for (int ni=0;ni<4;ni++){
      float4 a = *(const float4*)&aL[h*64 + ni*16 + l4*4];
      float4 bvv = *(const float4*)&aR[h*64 + ni*16 + l4*4];
      aLv[ni][0]=a.x; aLv[ni][1]=a.y; aLv[ni][2]=a.z; aLv[ni][3]=a.w;
      aRv[ni][0]=bvv.x; aRv[ni][1]=bvv.y; aRv[ni][2]=bvv.z; aRv[ni][3]=bvv.w;
    }
    #pragma unroll
    for (int mi=0;mi<4;mi++){
      int row = bm*128 + wr*64 + mi*16 + l15;
      float sl = 0.f, sr = 0.f;
      ushort4 packs[4];
      #pragma unroll
      for (int ni=0;ni<4;ni++){
        __hip_bfloat16 o[4];
        #pragma unroll
        for (int r=0;r<4;r++){
          float v = acc[mi][ni][r];
          sl += v*aLv[ni][r]; sr += v*aRv[ni][r];
          o[r] = __float2bfloat16(v);
        }
        packs[ni] = *(ushort4*)o;
      }
      if (row < M){
        #pragma unroll
        for (int ni=0;ni<4;ni++)
          *(ushort4*)&Fb[(size_t)row*256 + h*64 + ni*16 + l4*4] = packs[ni];
      }
      sl += __shfl_xor(sl, 16); sl += __shfl_xor(sl, 32);
      sr += __shfl_xor(sr, 16); sr += __shfl_xor(sr, 32);
      if (l4 == 0 && row < M){ el[row*4 + h] = sl; er[row*4 + h] = sr; }
    }
  } else {
    if (wc == 0){
      float aLv[4][4], aRv[4][4];
      #pragma unroll
      for (int ni=0;ni<4;ni++){
        float4 a = *(const float4*)&aL[ni*16 + l4*4];
        float4 bvv = *(const float4*)&aR[ni*16 + l4*4];
        aLv[ni][0]=a.x; aLv[ni][1]=a.y; aLv[ni][2]=a.z; aLv[ni][3]=a.w;
        aRv[ni][0]=bvv.x; aRv[ni][1]=bvv.y; aRv[ni][2]=bvv.z; aRv[ni][3]=bvv.w;
      }
      #pragma unroll
      for (int mi=0;mi<4;mi++){
        int row = bm*128 + wr*64 + mi*16 + l15;
        float sl = 0.f, sr = 0.f;
        ushort4 packs[4];
        #pragma unroll
        for (int ni=0;ni<4;ni++){
          __hip_bfloat16 o[4];
          #pragma unroll
          for (int r=0;r<4;r++){
            float v = acc[mi][ni][r];
            sl += v*aLv[ni][r]; sr += v*aRv[ni][r];
            o[r] = __float2bfloat16(v);
          }
          packs[ni] = *(ushort4*)o;
        }
        if (row < M){
          #pragma unroll
          for (int ni=0;ni<4;ni++)
            *(ushort4*)&Fb[(size_t)row*64 + ni*16 + l4*4] = packs[ni];
        }
        sl += __shfl_xor(sl, 16); sl += __shfl_xor(sl, 32);
        sr += __shfl_xor(sr, 16); sr += __shfl_xor(sr, 32);
        if (l4 == 0 && row < M){ el[row] = sl; er[row] = sr; }
      }
    } else {
      #pragma unroll
      for (int mi=0;mi<4;mi++){
        int row = bm*128 + wr*64 + mi*16 + l15;
        if (row < M){
          #pragma unroll
          for (int ni=0;ni<4;ni++){
            float4 o = make_float4(acc[mi][ni][0], acc[mi][ni][1], acc[mi][ni][2], acc[mi][ni][3]);
            *(float4*)&Res[(size_t)row*64 + ni*16 + l4*4] = o;
          }
        }
      }
    }
  }
}

// fused dispatch: blocks [0,800) = layer-1 GEMM (XCD-paired swizzle);
// rest = atomic-free CSR fill (slot precomputed in hist).
__global__ __launch_bounds__(256) void gemm1_fill_kernel(
    const float* __restrict__ x, const __hip_bfloat16* __restrict__ W1T,
    __hip_bfloat16* __restrict__ featb,
    float* __restrict__ el, float* __restrict__ er,
    const float* __restrict__ aL, const float* __restrict__ aR,
    const int* __restrict__ src, const int* __restrict__ dst,
    const int* __restrict__ row_ptr, const int* __restrict__ eslot,
    int* __restrict__ csr_src)
{
  int id = blockIdx.x;
  if (id < GEMM1_BLOCKS){
    int bn = (id >> 3) & 1;
    int bm = (id & 7) | ((id >> 4) << 3);
    if (bm*128 >= N_NODES) return;
    gemm_body<1,true>(x, W1T, featb, nullptr, el, er, aL, aR, N_NODES, bm, bn);
  } else {
    int e = (id - GEMM1_BLOCKS)*256 + threadIdx.x;
    if (e < N_EDGES){
      int d = dst[e];
      csr_src[row_ptr[d] + eslot[e]] = src[e];   // no atomics: slot from hist
    }
  }
}

__global__ __launch_bounds__(256) void gemm2_kernel(
    const __hip_bfloat16* __restrict__ A, const __hip_bfloat16* __restrict__ BT,
    __hip_bfloat16* __restrict__ Fb, float* __restrict__ Res,
    float* __restrict__ el, float* __restrict__ er,
    const float* __restrict__ aL, const float* __restrict__ aR, int M)
{
  gemm_body<2,false>(A, BT, Fb, Res, el, er, aL, aR, M, blockIdx.x, 0);
}

// ---------------- fused softmax + aggregation, LDS-staged weights (R10-proven form) ------

__global__ __launch_bounds__(256) void agg1_kernel(const int* __restrict__ row_ptr,
                                                   const int* __restrict__ csr_src,
                                                   const float* __restrict__ el,
                                                   const float* __restrict__ er,
                                                   const __hip_bfloat16* __restrict__ featb,
                                                   const float* __restrict__ bias,
                                                   __hip_bfloat16* __restrict__ h1b, int N){
  __shared__ int   ssh[4][CHUNK];
  __shared__ float wsh[4][CHUNK][4];
  int lane = threadIdx.x & 63, wv = threadIdx.x >> 6;
  int n = blockIdx.x*4 + wv;
  if (n >= N) return;
  int rs = row_ptr[n], re = row_ptr[n+1];
  int half = lane >> 5;
  int l31 = lane & 31;
  int hl = l31 >> 3;                       // head of cols [l31*8, l31*8+8)
  float4 ern4 = *(const float4*)&er[(size_t)n*4];
  float ernv[4] = {ern4.x, ern4.y, ern4.z, ern4.w};
  float acc[8] = {0.f,0.f,0.f,0.f,0.f,0.f,0.f,0.f};
  float ssum4[4] = {0.f,0.f,0.f,0.f};

  for (int base = rs; base < re; base += CHUNK){
    int cnt = min(CHUNK, re - base);
    int padded = (cnt + 7) & ~7;
    // phase A: one lane per edge, exp computed once
    for (int t = lane; t < padded; t += 64){
      float w4[4] = {0.f,0.f,0.f,0.f};
      int s = 0;
      if (t < cnt){
        s = csr_src[base + t];
        float4 e4 = *(const float4*)&el[(size_t)s*4];
        float ev[4] = {e4.x, e4.y, e4.z, e4.w};
        #pragma unroll
        for (int h = 0; h < 4; h++){
          float e = ev[h] + ernv[h];
          e = e > 0.f ? e : 0.2f*e;
          float ex = __expf(e);
          w4[h] = ex;
          ssum4[h] += ex;
        }
      }
      ssh[wv][t] = s;
      *(float4*)&wsh[wv][t][0] = make_float4(w4[0], w4[1], w4[2], w4[3]);
    }
    // phase B: 8 edges per iteration, 4 independent 512B row loads per half-wave
    for (int jb = 0; jb < padded; jb += 8){
      int t0 = jb + half, t1 = jb + 2 + half, t2 = jb + 4 + half, t3 = jb + 6 + half;
      int s0 = ssh[wv][t0], s1 = ssh[wv][t1], s2 = ssh[wv][t2], s3 = ssh[wv][t3];
      float w0 = wsh[wv][t0][hl], w1 = wsh[wv][t1][hl];
      float w2 = wsh[wv][t2][hl], w3 = wsh[wv][t3][hl];
      short8v f0 = *(const short8v*)&featb[(size_t)s0*256 + l31*8];
      short8v f1 = *(const short8v*)&featb[(size_t)s1*256 + l31*8];
      short8v f2 = *(const short8v*)&featb[(size_t)s2*256 + l31*8];
      short8v f3 = *(const short8v*)&featb[(size_t)s3*256 + l31*8];
      #pragma unroll
      for (int q = 0; q < 8; q++){
        acc[q] += w0 * bf2f((unsigned short)f0[q]);
        acc[q] += w1 * bf2f((unsigned short)f1[q]);
        acc[q] += w2 * bf2f((unsigned short)f2[q]);
        acc[q] += w3 * bf2f((unsigned short)f3[q]);
      }
    }
  }
  #pragma unroll
  for (int off = 32; off; off >>= 1)
    #pragma unroll
    for (int h = 0; h < 4; h++) ssum4[h] += __shfl_xor(ssum4[h], off);
  #pragma unroll
  for (int q = 0; q < 8; q++) acc[q] += __shfl_xor(acc[q], 32);
  float inv = ssum4[hl] > 0.f ? 1.f/ssum4[hl] : 0.f;
  if (lane < 32){
    float4 b0 = *(const float4*)&bias[l31*8];
    float4 b1v = *(const float4*)&bias[l31*8 + 4];
    float bb[8] = {b0.x,b0.y,b0.z,b0.w,b1v.x,b1v.y,b1v.z,b1v.w};
    __hip_bfloat16 o[8];
    #pragma unroll
    for (int q = 0; q < 8; q++){
      float v = acc[q]*inv + bb[q];
      v = v > 0.f ? v : __expf(v) - 1.f;   // ELU
      o[q] = __float2bfloat16(v);
    }
    *(short8v*)&h1b[(size_t)n*256 + l31*8] = *(short8v*)o;
  }
}

__global__ __launch_bounds__(256) void agg2_kernel(const int* __restrict__ row_ptr,
                                                   const int* __restrict__ csr_src,
                                                   const float* __restrict__ el,
                                                   const float* __restrict__ er,
                                                   const __hip_bfloat16* __restrict__ f2b,
                                                   const float* __restrict__ res,
                                                   const float* __restrict__ bias,
                                                   float* __restrict__ out, int N){
  __shared__ int   ssh[4][CHUNK];
  __shared__ float wsh[4][CHUNK];
  int lane = threadIdx.x & 63, wv = threadIdx.x >> 6;
  int n = blockIdx.x*4 + wv;
  if (n >= N) return;
  int rs = row_ptr[n], re = row_ptr[n+1];
  int q4 = lane >> 4;                      // edge slot 0..3
  int l15 = lane & 15;
  float ern = er[n];
  float acc[4] = {0.f,0.f,0.f,0.f};
  float ssum = 0.f;

  for (int base = rs; base < re; base += CHUNK){
    int cnt = min(CHUNK, re - base);
    int padded = (cnt + 15) & ~15;
    for (int t = lane; t < padded; t += 64){
      float w = 0.f; int s = 0;
      if (t < cnt){
        s = csr_src[base + t];
        float e = el[s] + ern;
        e = e > 0.f ? e : 0.2f*e;
        w = __expf(e);
        ssum += w;
      }
      ssh[wv][t] = s;
      wsh[wv][t] = w;
    }
    for (int jb = 0; jb < padded; jb += 16){
      int t0 = jb + q4, t1 = jb + 4 + q4, t2 = jb + 8 + q4, t3 = jb + 12 + q4;
      int s0 = ssh[wv][t0], s1 = ssh[wv][t1], s2 = ssh[wv][t2], s3 = ssh[wv][t3];
      float w0 = wsh[wv][t0], w1 = wsh[wv][t1], w2 = wsh[wv][t2], w3 = wsh[wv][t3];
      ushort4 f0 = *(const ushort4*)&f2b[(size_t)s0*NC + l15*4];
      ushort4 f1 = *(const ushort4*)&f2b[(size_t)s1*NC + l15*4];
      ushort4 f2 = *(const ushort4*)&f2b[(size_t)s2*NC + l15*4];
      ushort4 f3 = *(const ushort4*)&f2b[(size_t)s3*NC + l15*4];
      acc[0] += w0*bf2f(f0.x) + w1*bf2f(f1.x) + w2*bf2f(f2.x) + w3*bf2f(f3.x);
      acc[1] += w0*bf2f(f0.y) + w1*bf2f(f1.y) + w2*bf2f(f2.y) + w3*bf2f(f3.y);
      acc[2] += w0*bf2f(f0.z) + w1*bf2f(f1.z) + w2*bf2f(f2.z) + w3*bf2f(f3.z);
      acc[3] += w0*bf2f(f0.w) + w1*bf2f(f1.w) + w2*bf2f(f2.w) + w3*bf2f(f3.w);
    }
  }
  #pragma unroll
  for (int off = 32; off; off >>= 1) ssum += __shfl_xor(ssum, off);
  #pragma unroll
  for (int q = 0; q < 4; q++){
    acc[q] += __shfl_xor(acc[q], 16);
    acc[q] += __shfl_xor(acc[q], 32);
  }
  float inv = ssum > 0.f ? 1.f/ssum : 0.f;
  if (lane < 16){
    float4 r4 = *(const float4*)&res[(size_t)n*NC + l15*4];
    float4 b4 = *(const float4*)&bias[l15*4];
    float4 o;
    o.x = acc[0]*inv + r4.x + b4.x;
    o.y = acc[1]*inv + r4.y + b4.y;
    o.z = acc[2]*inv + r4.z + b4.z;
    o.w = acc[3]*inv + r4.w + b4.w;
    *(float4*)&out[(size_t)n*NC + l15*4] = o;
  }
}

// ---------------- launch ----------------

extern "C" void kernel_launch(void* const* d_in, const int* in_sizes, int n_in,
                              void* d_out, int out_size, void* d_ws, size_t ws_size,
                              hipStream_t stream){
  const float* x     = (const float*)d_in[0];
  const float* W1    = (const float*)d_in[1];
  const float* aL1   = (const float*)d_in[2];
  const float* aR1   = (const float*)d_in[3];
  const float* b1    = (const float*)d_in[4];
  const float* W2    = (const float*)d_in[5];
  const float* aL2   = (const float*)d_in[6];
  const float* aR2   = (const float*)d_in[7];
  const float* b2    = (const float*)d_in[8];
  const float* resW2 = (const float*)d_in[9];
  const int*   src   = (const int*)d_in[10];
  const int*   dst   = (const int*)d_in[11];
  float* out = (float*)d_out;

  char* p = (char*)d_ws;
  auto alloc = [&](size_t bytes)->void*{
    void* r = (void*)p; p += (bytes + 255) & ~(size_t)255; return r;
  };
  __hip_bfloat16* featb = (__hip_bfloat16*)alloc((size_t)N_NODES*F1*2);
  __hip_bfloat16* h1b   = (__hip_bfloat16*)alloc((size_t)N_NODES*F1*2);
  __hip_bfloat16* f2b   = (__hip_bfloat16*)alloc((size_t)N_NODES*NC*2);
  float* res   = (float*)alloc((size_t)N_NODES*NC*4);
  float* el1   = (float*)alloc((size_t)N_NODES*H1*4);
  float* er1   = (float*)alloc((size_t)N_NODES*H1*4);
  float* el2   = (float*)alloc((size_t)N_NODES*4);
  float* er2   = (float*)alloc((size_t)N_NODES*4);
  int* counts  = (int*)alloc((size_t)N_NODES*4);
  int* part    = (int*)alloc((size_t)N_NODES*4);
  int* bsum    = (int*)alloc((size_t)64*4);
  int* row_ptr = (int*)alloc((size_t)(N_NODES+1)*4);
  int* eslot   = (int*)alloc((size_t)N_EDGES*4);
  int* csr_src = (int*)alloc((size_t)N_EDGES*4);
  __hip_bfloat16* W1T = (__hip_bfloat16*)alloc((size_t)256*256*2);
  __hip_bfloat16* B2T = (__hip_bfloat16*)alloc((size_t)128*256*2);

  int nb = (N_NODES + 1023)/1024;
  int prepw_blocks = (256*256 + 128*256 + 255)/256;
  hipMemsetAsync(counts, 0, (size_t)N_NODES*4, stream);
  hist_prepw_kernel<<<HIST4_BLOCKS + prepw_blocks, 256, 0, stream>>>(dst, counts, eslot,
                                                                     W1, W2, resW2, W1T, B2T);
  scan1_kernel<<<nb, 1024, 0, stream>>>(counts, part, bsum, N_NODES);
  scan3_kernel<<<nb, 1024, 0, stream>>>(part, bsum, row_ptr, N_NODES);

  // fused: layer-1 GEMM (blocks 0..799, XCD-paired) + atomic-free CSR fill (blocks 800..)
  gemm1_fill_kernel<<<GEMM1_BLOCKS + FILL_BLOCKS, 256, 0, stream>>>(
      x, W1T, featb, el1, er1, aL1, aR1, src, dst, row_ptr, eslot, csr_src);

  agg1_kernel<<<(N_NODES+3)/4, 256, 0, stream>>>(row_ptr, csr_src, el1, er1, featb, b1, h1b, N_NODES);

  gemm2_kernel<<<(N_NODES+127)/128, 256, 0, stream>>>(h1b, B2T, f2b, res,
                                                      el2, er2, aL2, aR2, N_NODES);
  agg2_kernel<<<(N_NODES+3)/4, 256, 0, stream>>>(row_ptr, csr_src, el2, er2, f2b, res, b2, out, N_NODES);
}